// Round 5
// baseline (133.110 us; speedup 1.0000x reference)
//
#include <hip/hip_runtime.h>
#include <stdint.h>

#define EMBED 384
#define NHEAD 6
#define HSZ   64
#define BATCH 32
#define SEQ   768
#define MROWS (BATCH * SEQ)   // 24576
#define NTILE (SEQ / 64)      // 12

typedef __bf16 bf16x8 __attribute__((ext_vector_type(8)));
typedef float  f32x4  __attribute__((ext_vector_type(4)));

#define GLD16(gp, lp)                                                        \
  __builtin_amdgcn_global_load_lds(                                          \
      (const __attribute__((address_space(1))) void*)(gp),                   \
      (__attribute__((address_space(3))) void*)(lp), 16, 0, 0)

#define QSCALE 0.18033688011112042f   /* 0.125 * log2(e): exp2-domain scores */

__device__ inline unsigned short nbf(float f) {   // native RNE convert
  union { __bf16 b; unsigned short s; } c; c.b = (__bf16)f; return c.s;
}
__device__ inline uint32_t pk2(float a, float b) { // -> v_cvt_pk_bf16_f32
  union { __bf16 b[2]; uint32_t u; } c;
  c.b[0] = (__bf16)a; c.b[1] = (__bf16)b; return c.u;
}

// ---------------- fp32 -> bf16 convert (weights only, X handled in-GEMM) ----
__global__ __launch_bounds__(256) void cvtW(const float* __restrict__ a,
                                            const float* __restrict__ b,
                                            const float* __restrict__ c,
                                            const float* __restrict__ d,
                                            unsigned short* __restrict__ dst) {
  const int NWc = EMBED * EMBED;
  int i = (blockIdx.x * 256 + threadIdx.x) * 4;
  int wsel = i / NWc, r = i - wsel * NWc;
  const float* s = ((wsel == 0) ? a : (wsel == 1) ? b : (wsel == 2) ? c : d) + r;
  float4 v = *reinterpret_cast<const float4*>(s);
  uint2 o;
  o.x = pk2(v.x, v.y); o.y = pk2(v.z, v.w);
  *reinterpret_cast<uint2*>(dst + i) = o;
}

// ---------------- GEMM: C[m,n] = sum_k A[m,k] * B[n,k]  (B stored [N][K]) ----
// MODE 0: A is fp32 (staged raw, converted on fragment read); scatters Q/K bf16
//         (Q scaled by QSCALE); V written transposed to VT[bh][d][t].
// MODE 1: A bf16; fp32 out + bias.
template <int MODE>
__global__ __launch_bounds__(256) void gemm_bt(
    const void* __restrict__ Ap,
    const unsigned short* __restrict__ Bw,
    unsigned short* __restrict__ Qb,
    unsigned short* __restrict__ Kb,
    unsigned short* __restrict__ VT,
    float* __restrict__ Co,
    const float* __restrict__ bias) {
  // MODE0: A f32 128x64 (32KB) + B bf16 128x64 (16KB) = 48KB (epilogue reuses 32KB)
  // MODE1: A bf16 (16KB) + B bf16 (16KB) = 32KB
  __shared__ __align__(16) short SH[MODE == 0 ? 24576 : 16384];
  const int tid = threadIdx.x;
  const int lane = tid & 63;
  const int w = tid >> 6;
  const int wm = w >> 1, wn = w & 1;
  const int m0 = blockIdx.x * 128, n0 = blockIdx.y * 128;
  const int l15 = lane & 15, lg = lane >> 4;
  char* Ac = (char*)SH;
  short* Bt = SH + (MODE == 0 ? 16384 : 8192);
  char* Bc = (char*)Bt;
  char* shc = (char*)SH;

  f32x4 acc[4][4];
#pragma unroll
  for (int i = 0; i < 4; ++i)
#pragma unroll
    for (int j = 0; j < 4; ++j) acc[i][j] = f32x4{0.f, 0.f, 0.f, 0.f};

#pragma unroll 1
  for (int kt = 0; kt < 6; ++kt) {
    const int k0 = kt * 64;
    __syncthreads();
    if (MODE == 0) {
      // A fp32: 128 rows x 16 units(16B); swizzle unit' = c ^ (row&15)
      const float* A = (const float*)Ap;
#pragma unroll
      for (int j = 0; j < 8; ++j) {
        const int v = j * 256 + tid;
        const int row = v >> 4, p = v & 15;
        const int c = p ^ (row & 15);
        GLD16(A + (size_t)(m0 + row) * EMBED + k0 + c * 4,
              Ac + (j * 256 + (tid & ~63)) * 16);
      }
    } else {
      const unsigned short* A = (const unsigned short*)Ap;
#pragma unroll
      for (int j = 0; j < 4; ++j) {
        const int u = j * 256 + tid;
        const int row = u >> 3, un = u & 7;
        GLD16(A + (size_t)(m0 + row) * EMBED + k0 + (un ^ (row & 7)) * 8,
              Ac + (j * 256 + (tid & ~63)) * 16);
      }
    }
#pragma unroll
    for (int j = 0; j < 4; ++j) {
      const int u = j * 256 + tid;
      const int row = u >> 3, un = u & 7;
      GLD16(Bw + (size_t)(n0 + row) * EMBED + k0 + (un ^ (row & 7)) * 8,
            Bc + (j * 256 + (tid & ~63)) * 16);
    }
    __syncthreads();
#pragma unroll
    for (int kc = 0; kc < 2; ++kc) {
      bf16x8 af[4], bfr[4];
#pragma unroll
      for (int mt = 0; mt < 4; ++mt) {
        const int row = wm * 64 + mt * 16 + l15;
        if (MODE == 0) {
          const int c0 = kc * 8 + lg * 2;
          const f32x4 lo = *(const f32x4*)(Ac + row * 256 + ((c0 ^ (row & 15)) * 16));
          const f32x4 hi = *(const f32x4*)(Ac + row * 256 + (((c0 + 1) ^ (row & 15)) * 16));
          union { uint32_t u[4]; bf16x8 v; } cv;
          cv.u[0] = pk2(lo[0], lo[1]); cv.u[1] = pk2(lo[2], lo[3]);
          cv.u[2] = pk2(hi[0], hi[1]); cv.u[3] = pk2(hi[2], hi[3]);
          af[mt] = cv.v;
        } else {
          af[mt] = *(const bf16x8*)(Ac + row * 128 + (((kc * 4 + lg) ^ (row & 7)) * 16));
        }
      }
#pragma unroll
      for (int nt = 0; nt < 4; ++nt) {
        const int row = wn * 64 + nt * 16 + l15;
        bfr[nt] = *(const bf16x8*)(Bc + row * 128 + (((kc * 4 + lg) ^ (row & 7)) * 16));
      }
#pragma unroll
      for (int mt = 0; mt < 4; ++mt)
#pragma unroll
        for (int nt = 0; nt < 4; ++nt)
          acc[mt][nt] = __builtin_amdgcn_mfma_f32_16x16x32_bf16(
              af[mt], bfr[nt], acc[mt][nt], 0, 0, 0);
    }
  }

  if (MODE == 0 && n0 >= 768) {
    // ---- V blocks: transpose via LDS, write VT[bh][d][t] coalesced ----
    const int b = m0 / SEQ, t0 = m0 - b * SEQ;
    __syncthreads();
#pragma unroll
    for (int mt = 0; mt < 4; ++mt)
#pragma unroll
      for (int nt = 0; nt < 4; ++nt)
#pragma unroll
        for (int r = 0; r < 4; ++r) {
          const int tl = wm * 64 + mt * 16 + lg * 4 + r;
          const int nl = wn * 64 + nt * 16 + l15;
          *(unsigned short*)(shc + nl * 256 + (((tl >> 3) ^ (nl & 7)) * 16) +
                             (tl & 7) * 2) = nbf(acc[mt][nt][r]);
        }
    __syncthreads();
#pragma unroll
    for (int j = 0; j < 8; ++j) {
      const int u = j * 256 + tid;
      const int row = u >> 4, un = u & 15;
      int4 vv = *(const int4*)(shc + row * 256 + ((un ^ (row & 7)) * 16));
      const int cg = (n0 - 768) + row;
      const int h = cg >> 6, d = cg & 63;
      *(int4*)(VT + ((size_t)(b * NHEAD + h) * HSZ + d) * SEQ + t0 + un * 8) = vv;
    }
    return;
  }

#pragma unroll
  for (int mt = 0; mt < 4; ++mt) {
#pragma unroll
    for (int nt = 0; nt < 4; ++nt) {
#pragma unroll
      for (int r = 0; r < 4; ++r) {
        const int m = m0 + wm * 64 + mt * 16 + lg * 4 + r;
        const int n = n0 + wn * 64 + nt * 16 + l15;
        const float v = acc[mt][nt][r];
        if (MODE == 0) {
          const int which = n / EMBED;   // 0=Q, 1=K here (V handled above)
          const int c = n - which * EMBED;
          const int h = c >> 6, d = c & 63;
          const int b = m / SEQ, t = m - b * SEQ;
          const size_t off = ((size_t)((b * NHEAD + h) * SEQ + t)) * HSZ + d;
          unsigned short* dstp = (which == 0) ? Qb : Kb;
          dstp[off] = nbf(which == 0 ? v * QSCALE : v);
        } else {
          Co[(size_t)m * EMBED + n] = v + bias[n];
        }
      }
    }
  }
}

// ---------------- flash attention, causal, paired q-tiles, swapped operands --
// grid (8, 144): bh = (by/6)*8+bx groups same-bh blocks on one XCD.
// Joint phase (kt<=qtA) processes BOTH q-tiles in one straight-line body.
__global__ __launch_bounds__(256, 2) void attn(const unsigned short* __restrict__ Qb,
                                               const unsigned short* __restrict__ Kb,
                                               const unsigned short* __restrict__ VT,
                                               unsigned short* __restrict__ AO) {
  __shared__ __align__(16) short Kt[2][64 * 64];   // [kv][d] swizzled, dbuf
  __shared__ __align__(16) short Vt[2][64 * 64];   // [d][kv] swizzled, dbuf
  __shared__ __align__(16) short Pl[4][16 * 64];   // per-wave P[q][kv] swizzled
  const int tid = threadIdx.x, lane = tid & 63, w = tid >> 6;
  const int l15 = lane & 15, lg = lane >> 4;
  const int bh = (blockIdx.y / 6) * 8 + blockIdx.x;
  const int qtA = blockIdx.y % 6, qtB = (NTILE - 1) - qtA;
  const size_t base = (size_t)bh * SEQ * HSZ;      // Qb/Kb [bh][t][d]
  char* pw = (char*)(&Pl[w][0]);

  bf16x8 qfA[2], qfB[2];
#pragma unroll
  for (int kc = 0; kc < 2; ++kc) {
    qfA[kc] = *(const bf16x8*)(Qb + base + (size_t)(qtA * 64 + w * 16 + l15) * HSZ +
                               kc * 32 + lg * 8);
    qfB[kc] = *(const bf16x8*)(Qb + base + (size_t)(qtB * 64 + w * 16 + l15) * HSZ +
                               kc * 32 + lg * 8);
  }

  f32x4 oA[4], oB[4];
  float mA = -3.0e38f, lA = 0.f, mB = -3.0e38f, lB = 0.f;   // l = per-lane partial
#pragma unroll
  for (int nt = 0; nt < 4; ++nt) {
    oA[nt] = f32x4{0.f, 0.f, 0.f, 0.f};
    oB[nt] = f32x4{0.f, 0.f, 0.f, 0.f};
  }

  auto stage = [&](int kt, int buf) {
#pragma unroll
    for (int j = 0; j < 2; ++j) {
      const int u = j * 256 + tid;
      const int row = u >> 3, un = u & 7;
      const int sw = (un ^ (row & 7)) * 8;
      const int ub = (j * 256 + (tid & ~63)) * 8;
      GLD16(Kb + base + (size_t)(kt * 64 + row) * HSZ + sw, &Kt[buf][ub]);
      GLD16(VT + base + (size_t)row * SEQ + kt * 64 + sw, &Vt[buf][ub]);
    }
  };

  bf16x8 kf[2][4], vf[2][4];
  auto ldkv = [&](int buf) {
    const char* Kc = (const char*)Kt[buf];
    const char* Vc = (const char*)Vt[buf];
#pragma unroll
    for (int kc = 0; kc < 2; ++kc)
#pragma unroll
      for (int nt = 0; nt < 4; ++nt) {
        const int row = nt * 16 + l15;
        const int sw = ((kc * 4 + lg) ^ (row & 7)) * 16;
        kf[kc][nt] = *(const bf16x8*)(Kc + row * 128 + sw);
        vf[kc][nt] = *(const bf16x8*)(Vc + row * 128 + sw);
      }
  };

  auto qk = [&](const bf16x8* qf, f32x4* s) {
#pragma unroll
    for (int nt = 0; nt < 4; ++nt) s[nt] = f32x4{0.f, 0.f, 0.f, 0.f};
    __builtin_amdgcn_s_setprio(1);
#pragma unroll
    for (int kc = 0; kc < 2; ++kc)
#pragma unroll
      for (int nt = 0; nt < 4; ++nt)
        s[nt] = __builtin_amdgcn_mfma_f32_16x16x32_bf16(kf[kc][nt], qf[kc], s[nt],
                                                        0, 0, 0);
    __builtin_amdgcn_s_setprio(0);
  };

  auto mask = [&](f32x4* s) {
#pragma unroll
    for (int nt = 0; nt < 4; ++nt)
#pragma unroll
      for (int r = 0; r < 4; ++r)
        if (nt * 16 + lg * 4 + r > w * 16 + l15) s[nt][r] = -3.0e38f;
  };

  // softmax (exp2 domain, defer-rescale, deferred cross-lane l) + P pack + PV
  auto smpv = [&](f32x4* s, f32x4* o, float& m, float& lp) {
    float t0 = fmaxf(fmaxf(fmaxf(s[0][0], s[0][1]), s[0][2]), s[0][3]);
    float t1 = fmaxf(fmaxf(fmaxf(s[1][0], s[1][1]), s[1][2]), s[1][3]);
    float t2 = fmaxf(fmaxf(fmaxf(s[2][0], s[2][1]), s[2][2]), s[2][3]);
    float t3 = fmaxf(fmaxf(fmaxf(s[3][0], s[3][1]), s[3][2]), s[3][3]);
    float mx = fmaxf(fmaxf(t0, t1), fmaxf(t2, t3));
    mx = fmaxf(mx, __shfl_xor(mx, 16, 64));
    mx = fmaxf(mx, __shfl_xor(mx, 32, 64));
    if (!__all(mx <= m + 8.f)) {          // P bounded by 2^8
      const float mn = fmaxf(m, mx);
      const float a = __builtin_amdgcn_exp2f(m - mn);
      m = mn;
      lp *= a;
#pragma unroll
      for (int nt = 0; nt < 4; ++nt) o[nt] *= a;
    }
    float srow = 0.f;
#pragma unroll
    for (int nt = 0; nt < 4; ++nt)
#pragma unroll
      for (int r = 0; r < 4; ++r) {
        const float e = __builtin_amdgcn_exp2f(s[nt][r] - m);
        s[nt][r] = e;
        srow += e;
      }
    lp += srow;
#pragma unroll
    for (int nt = 0; nt < 4; ++nt) {
      const int kv = nt * 16 + lg * 4;
      int2 pv;
      pv.x = (int)pk2(s[nt][0], s[nt][1]);
      pv.y = (int)pk2(s[nt][2], s[nt][3]);
      *(int2*)(pw + l15 * 128 + (((kv >> 3) ^ (l15 & 7)) * 16) + (kv & 7) * 2) = pv;
    }
    asm volatile("" ::: "memory");
    bf16x8 pf[2];
#pragma unroll
    for (int kc = 0; kc < 2; ++kc)
      pf[kc] = *(const bf16x8*)(pw + l15 * 128 + (((kc * 4 + lg) ^ (l15 & 7)) * 16));
    asm volatile("" ::: "memory");
    __builtin_amdgcn_s_setprio(1);
#pragma unroll
    for (int kc = 0; kc < 2; ++kc)
#pragma unroll
      for (int nt = 0; nt < 4; ++nt)
        o[nt] = __builtin_amdgcn_mfma_f32_16x16x32_bf16(vf[kc][nt], pf[kc], o[nt],
                                                        0, 0, 0);
    __builtin_amdgcn_s_setprio(0);
  };

  int cur = 0;
  auto joint = [&](int kt, bool diagA) {
    __syncthreads();
    if (kt < qtB) stage(kt + 1, cur ^ 1);
    ldkv(cur);
    f32x4 sB[4], sA[4];
    qk(qfB, sB);
    qk(qfA, sA);
    if (diagA) mask(sA);
    smpv(sB, oB, mB, lB);
    smpv(sA, oA, mA, lA);
    cur ^= 1;
  };
  auto single = [&](int kt, bool diagB) {
    __syncthreads();
    if (kt < qtB) stage(kt + 1, cur ^ 1);
    ldkv(cur);
    f32x4 sB[4];
    qk(qfB, sB);
    if (diagB) mask(sB);
    smpv(sB, oB, mB, lB);
    cur ^= 1;
  };

  stage(0, 0);
#pragma unroll 1
  for (int kt = 0; kt < qtA; ++kt) joint(kt, false);
  joint(qtA, true);
#pragma unroll 1
  for (int kt = qtA + 1; kt < qtB; ++kt) single(kt, false);
  single(qtB, true);

  // epilogue: finish deferred l-reduction; lane holds O[q=l15][d=nt*16+lg*4+r]
  float ltA = lA, ltB = lB;
  ltA += __shfl_xor(ltA, 16, 64); ltA += __shfl_xor(ltA, 32, 64);
  ltB += __shfl_xor(ltB, 16, 64); ltB += __shfl_xor(ltB, 32, 64);
  const float invA = 1.f / ltA, invB = 1.f / ltB;
  const int bq = bh / NHEAD, h = bh - bq * NHEAD;
#pragma unroll
  for (int nt = 0; nt < 4; ++nt) {
    ushort4 sa, sb;
    sa.x = nbf(oA[nt][0] * invA); sa.y = nbf(oA[nt][1] * invA);
    sa.z = nbf(oA[nt][2] * invA); sa.w = nbf(oA[nt][3] * invA);
    sb.x = nbf(oB[nt][0] * invB); sb.y = nbf(oB[nt][1] * invB);
    sb.z = nbf(oB[nt][2] * invB); sb.w = nbf(oB[nt][3] * invB);
    const int col = h * HSZ + nt * 16 + lg * 4;
    *(ushort4*)(AO + ((size_t)(bq * SEQ + qtA * 64 + w * 16 + l15)) * EMBED + col) = sa;
    *(ushort4*)(AO + ((size_t)(bq * SEQ + qtB * 64 + w * 16 + l15)) * EMBED + col) = sb;
  }
}

extern "C" void kernel_launch(void* const* d_in, const int* in_sizes, int n_in,
                              void* d_out, int out_size, void* d_ws, size_t ws_size,
                              hipStream_t stream) {
  const float* X  = (const float*)d_in[0];
  const float* Wq = (const float*)d_in[1];
  const float* Wk = (const float*)d_in[2];
  const float* Wv = (const float*)d_in[3];
  const float* Wo = (const float*)d_in[4];
  const float* bo = (const float*)d_in[5];
  float* out = (float*)d_out;

  const size_t NW = (size_t)EMBED * EMBED;   // 147456
  const size_t NX = (size_t)MROWS * EMBED;   // 9437184
  unsigned short* ws    = (unsigned short*)d_ws;
  unsigned short* Wqkvb = ws;                // 3*NW
  unsigned short* Wob   = Wqkvb + 3 * NW;    // NW
  unsigned short* AOb   = Wob + NW;          // NX  (attn output, bf16)
  unsigned short* Qb    = AOb + NX;          // NX  [B,H,T,D]
  unsigned short* Kb    = Qb + NX;           // NX  [B,H,T,D]
  unsigned short* VTb   = Kb + NX;           // NX  [B,H,D,T] (transposed V)

  cvtW<<<(int)(4 * NW / 4 / 256), 256, 0, stream>>>(Wq, Wk, Wv, Wo, Wqkvb);

  gemm_bt<0><<<dim3(MROWS / 128, (3 * EMBED) / 128), 256, 0, stream>>>(
      X, Wqkvb, Qb, Kb, VTb, nullptr, nullptr);

  attn<<<dim3(8, 144), 256, 0, stream>>>(Qb, Kb, VTb, AOb);

  gemm_bt<1><<<dim3(MROWS / 128, EMBED / 128), 256, 0, stream>>>(
      AOb, Wob, nullptr, nullptr, nullptr, out, bo);
}

// Round 6
// 108.878 us; speedup vs baseline: 1.2226x; 1.2226x over previous
//
#include <hip/hip_runtime.h>
#include <stdint.h>

#define EMBED 384
#define NHEAD 6
#define HSZ   64
#define BATCH 32
#define SEQ   768
#define MROWS (BATCH * SEQ)   // 24576
#define NTILE (SEQ / 64)      // 12

typedef __bf16 bf16x8 __attribute__((ext_vector_type(8)));
typedef float  f32x4  __attribute__((ext_vector_type(4)));

#define GLD16(gp, lp)                                                        \
  __builtin_amdgcn_global_load_lds(                                          \
      (const __attribute__((address_space(1))) void*)(gp),                   \
      (__attribute__((address_space(3))) void*)(lp), 16, 0, 0)

__device__ inline unsigned short nbf(float f) {   // native RNE convert
  union { __bf16 b; unsigned short s; } c; c.b = (__bf16)f; return c.s;
}
__device__ inline uint32_t pk2(float a, float b) { // -> v_cvt_pk_bf16_f32
  union { __bf16 b[2]; uint32_t u; } c;
  c.b[0] = (__bf16)a; c.b[1] = (__bf16)b; return c.u;
}

// ---------------- fused fp32 -> bf16 convert: X then Wq|Wk|Wv|Wo ------------
__global__ __launch_bounds__(256) void cvtAll(const float* __restrict__ X,
                                              const float* __restrict__ Wq,
                                              const float* __restrict__ Wk,
                                              const float* __restrict__ Wv,
                                              const float* __restrict__ Wo,
                                              unsigned short* __restrict__ dstW,
                                              unsigned short* __restrict__ dstX) {
  const int NX = MROWS * EMBED, NW = EMBED * EMBED;
  int i = (blockIdx.x * 256 + threadIdx.x) * 4;
  const float* src;
  unsigned short* dst;
  if (i < NX) {
    src = X + i; dst = dstX + i;
  } else {
    int j = i - NX;
    int wsel = j / NW, r = j - wsel * NW;
    src = ((wsel == 0) ? Wq : (wsel == 1) ? Wk : (wsel == 2) ? Wv : Wo) + r;
    dst = dstW + j;
  }
  float4 v = *reinterpret_cast<const float4*>(src);
  uint2 o;
  o.x = pk2(v.x, v.y); o.y = pk2(v.z, v.w);
  *reinterpret_cast<uint2*>(dst) = o;
}

// ---------------- GEMM: C[m,n] = sum_k A[m,k] * B[n,k]  (B stored [N][K]) ----
// 2-phase double-buffered global_load_lds staging (1 barrier per K-step).
// MODE 0: scatters Q/K bf16 (Q scaled 0.125); V written transposed VT[bh][d][t].
// MODE 1: fp32 out + bias.
template <int MODE>
__global__ __launch_bounds__(256) void gemm_bt(
    const unsigned short* __restrict__ Ab,
    const unsigned short* __restrict__ Bw,
    unsigned short* __restrict__ Qb,
    unsigned short* __restrict__ Kb,
    unsigned short* __restrict__ VT,
    float* __restrict__ Co,
    const float* __restrict__ bias) {
  __shared__ __align__(16) short SH[32768];   // 64KB: 2 bufs x (A 16KB + B 16KB)
  const int tid = threadIdx.x;
  const int lane = tid & 63;
  const int w = tid >> 6;
  const int wm = w >> 1, wn = w & 1;
  const int m0 = blockIdx.x * 128, n0 = blockIdx.y * 128;
  const int l15 = lane & 15, lg = lane >> 4;
  char* shc = (char*)SH;

  auto stage = [&](int kt, int buf) {
    short* At = SH + buf * 16384;
    short* Bt = At + 8192;
    const int k0 = kt * 64;
#pragma unroll
    for (int j = 0; j < 4; ++j) {
      const int u = j * 256 + tid;
      const int row = u >> 3, un = u & 7;
      const int sw = (un ^ (row & 7)) * 8;
      const int ub = (j * 256 + (tid & ~63)) * 8;
      GLD16(Ab + (size_t)(m0 + row) * EMBED + k0 + sw, At + ub);
      GLD16(Bw + (size_t)(n0 + row) * EMBED + k0 + sw, Bt + ub);
    }
  };

  f32x4 acc[4][4];
#pragma unroll
  for (int i = 0; i < 4; ++i)
#pragma unroll
    for (int j = 0; j < 4; ++j) acc[i][j] = f32x4{0.f, 0.f, 0.f, 0.f};

  stage(0, 0);
  int cur = 0;
#pragma unroll 1
  for (int kt = 0; kt < 6; ++kt) {
    __syncthreads();                        // drains stage(kt) [vmcnt(0) auto]
    if (kt < 5) stage(kt + 1, cur ^ 1);     // next-tile loads fly under MFMA
    const char* Ac = shc + cur * 32768;
    const char* Bc = Ac + 16384;
#pragma unroll
    for (int kc = 0; kc < 2; ++kc) {
      bf16x8 af[4], bfr[4];
#pragma unroll
      for (int mt = 0; mt < 4; ++mt) {
        const int row = wm * 64 + mt * 16 + l15;
        af[mt] = *(const bf16x8*)(Ac + row * 128 + (((kc * 4 + lg) ^ (row & 7)) * 16));
      }
#pragma unroll
      for (int nt = 0; nt < 4; ++nt) {
        const int row = wn * 64 + nt * 16 + l15;
        bfr[nt] = *(const bf16x8*)(Bc + row * 128 + (((kc * 4 + lg) ^ (row & 7)) * 16));
      }
#pragma unroll
      for (int mt = 0; mt < 4; ++mt)
#pragma unroll
        for (int nt = 0; nt < 4; ++nt)
          acc[mt][nt] = __builtin_amdgcn_mfma_f32_16x16x32_bf16(
              af[mt], bfr[nt], acc[mt][nt], 0, 0, 0);
    }
    cur ^= 1;
  }

  if (MODE == 0 && n0 >= 768) {
    // ---- V blocks: transpose via LDS (reuse buf0, 32KB), write VT coalesced --
    const int b = m0 / SEQ, t0 = m0 - b * SEQ;
    __syncthreads();
#pragma unroll
    for (int mt = 0; mt < 4; ++mt)
#pragma unroll
      for (int nt = 0; nt < 4; ++nt)
#pragma unroll
        for (int r = 0; r < 4; ++r) {
          const int tl = wm * 64 + mt * 16 + lg * 4 + r;
          const int nl = wn * 64 + nt * 16 + l15;
          *(unsigned short*)(shc + nl * 256 + (((tl >> 3) ^ (nl & 7)) * 16) +
                             (tl & 7) * 2) = nbf(acc[mt][nt][r]);
        }
    __syncthreads();
#pragma unroll
    for (int j = 0; j < 8; ++j) {
      const int u = j * 256 + tid;
      const int row = u >> 4, un = u & 15;
      int4 vv = *(const int4*)(shc + row * 256 + ((un ^ (row & 7)) * 16));
      const int cg = (n0 - 768) + row;
      const int h = cg >> 6, d = cg & 63;
      *(int4*)(VT + ((size_t)(b * NHEAD + h) * HSZ + d) * SEQ + t0 + un * 8) = vv;
    }
    return;
  }

#pragma unroll
  for (int mt = 0; mt < 4; ++mt) {
#pragma unroll
    for (int nt = 0; nt < 4; ++nt) {
#pragma unroll
      for (int r = 0; r < 4; ++r) {
        const int m = m0 + wm * 64 + mt * 16 + lg * 4 + r;
        const int n = n0 + wn * 64 + nt * 16 + l15;
        const float v = acc[mt][nt][r];
        if (MODE == 0) {
          const int which = n / EMBED;   // 0=Q, 1=K here (V handled above)
          const int c = n - which * EMBED;
          const int h = c >> 6, d = c & 63;
          const int b = m / SEQ, t = m - b * SEQ;
          const size_t off = ((size_t)((b * NHEAD + h) * SEQ + t)) * HSZ + d;
          unsigned short* dstp = (which == 0) ? Qb : Kb;
          dstp[off] = nbf(which == 0 ? v * 0.125f : v);  // fold 1/sqrt(D) into Q
        } else {
          Co[(size_t)m * EMBED + n] = v + bias[n];
        }
      }
    }
  }
}

// ---------------- flash attention (R3-verbatim: best measured 45.0 us) -------
// grid (8, 144): bh = (by/6)*8+bx groups same-bh blocks on one XCD.
__global__ __launch_bounds__(256, 3) void attn(const unsigned short* __restrict__ Qb,
                                               const unsigned short* __restrict__ Kb,
                                               const unsigned short* __restrict__ VT,
                                               unsigned short* __restrict__ AO) {
  __shared__ __align__(16) short Kt[2][64 * 64];   // [kv][d] swizzled, dbuf
  __shared__ __align__(16) short Vt[2][64 * 64];   // [d][kv] swizzled, dbuf
  __shared__ __align__(16) short Pl[4][16 * 64];   // per-wave P[q][kv] swizzled
  const int tid = threadIdx.x, lane = tid & 63, w = tid >> 6;
  const int l15 = lane & 15, lg = lane >> 4;
  const int bh = (blockIdx.y / 6) * 8 + blockIdx.x;
  const int qtA = blockIdx.y % 6, qtB = (NTILE - 1) - qtA;
  const size_t base = (size_t)bh * SEQ * HSZ;      // Qb/Kb [bh][t][d]
  char* pw = (char*)(&Pl[w][0]);

  bf16x8 qfA[2], qfB[2];
#pragma unroll
  for (int kc = 0; kc < 2; ++kc) {
    qfA[kc] = *(const bf16x8*)(Qb + base + (size_t)(qtA * 64 + w * 16 + l15) * HSZ +
                               kc * 32 + lg * 8);
    qfB[kc] = *(const bf16x8*)(Qb + base + (size_t)(qtB * 64 + w * 16 + l15) * HSZ +
                               kc * 32 + lg * 8);
  }

  f32x4 oA[4], oB[4];
  float mA = -3.0e38f, lA = 0.f, mB = -3.0e38f, lB = 0.f;
#pragma unroll
  for (int nt = 0; nt < 4; ++nt) {
    oA[nt] = f32x4{0.f, 0.f, 0.f, 0.f};
    oB[nt] = f32x4{0.f, 0.f, 0.f, 0.f};
  }

  auto stage = [&](int kt, int buf) {
#pragma unroll
    for (int j = 0; j < 2; ++j) {
      const int u = j * 256 + tid;
      const int row = u >> 3, un = u & 7;
      const int sw = (un ^ (row & 7)) * 8;
      const int ub = (j * 256 + (tid & ~63)) * 8;
      GLD16(Kb + base + (size_t)(kt * 64 + row) * HSZ + sw, &Kt[buf][ub]);
      GLD16(VT + base + (size_t)row * SEQ + kt * 64 + sw, &Vt[buf][ub]);
    }
  };

  // tile: S^T = mfma(K,Q); per-lane softmax (lane owns q=l15); O^T += mfma(V^T,P)
  auto tile = [&](const bf16x8* qf, const bf16x8 kf[2][4], const char* Vc,
                  f32x4* o, float& m, float& l, bool diag) {
    f32x4 s[4];
#pragma unroll
    for (int nt = 0; nt < 4; ++nt) s[nt] = f32x4{0.f, 0.f, 0.f, 0.f};
    __builtin_amdgcn_s_setprio(1);
#pragma unroll
    for (int kc = 0; kc < 2; ++kc)
#pragma unroll
      for (int nt = 0; nt < 4; ++nt)
        s[nt] = __builtin_amdgcn_mfma_f32_16x16x32_bf16(kf[kc][nt], qf[kc], s[nt],
                                                        0, 0, 0);
    __builtin_amdgcn_s_setprio(0);
    if (diag) {
#pragma unroll
      for (int nt = 0; nt < 4; ++nt)
#pragma unroll
        for (int r = 0; r < 4; ++r)
          if (nt * 16 + lg * 4 + r > w * 16 + l15) s[nt][r] = -3.0e38f;
    }
    float mx = s[0][0];
#pragma unroll
    for (int nt = 0; nt < 4; ++nt)
#pragma unroll
      for (int r = 0; r < 4; ++r) mx = fmaxf(mx, s[nt][r]);
    mx = fmaxf(mx, __shfl_xor(mx, 16, 64));
    mx = fmaxf(mx, __shfl_xor(mx, 32, 64));
    const float mn = fmaxf(m, mx);
    const float alpha = __expf(m - mn);
    m = mn;
    float srow = 0.f;
#pragma unroll
    for (int nt = 0; nt < 4; ++nt)
#pragma unroll
      for (int r = 0; r < 4; ++r) {
        const float e = __expf(s[nt][r] - mn);
        s[nt][r] = e;
        srow += e;
      }
    srow += __shfl_xor(srow, 16, 64);
    srow += __shfl_xor(srow, 32, 64);
    l = l * alpha + srow;
#pragma unroll
    for (int nt = 0; nt < 4; ++nt) o[nt] *= alpha;
    // P[q=l15][kv] -> LDS (b64 swizzled writes), packed bf16
#pragma unroll
    for (int nt = 0; nt < 4; ++nt) {
      const int kv = nt * 16 + lg * 4;
      int2 pv;
      pv.x = (int)pk2(s[nt][0], s[nt][1]);
      pv.y = (int)pk2(s[nt][2], s[nt][3]);
      *(int2*)(pw + l15 * 128 + (((kv >> 3) ^ (l15 & 7)) * 16) + (kv & 7) * 2) = pv;
    }
    asm volatile("" ::: "memory");
    bf16x8 pf[2];
#pragma unroll
    for (int kc = 0; kc < 2; ++kc)
      pf[kc] = *(const bf16x8*)(pw + l15 * 128 + (((kc * 4 + lg) ^ (l15 & 7)) * 16));
    __builtin_amdgcn_s_setprio(1);
#pragma unroll
    for (int kc = 0; kc < 2; ++kc)
#pragma unroll
      for (int nt = 0; nt < 4; ++nt) {
        const int row = nt * 16 + l15;
        bf16x8 vf = *(const bf16x8*)(Vc + row * 128 +
                                     (((kc * 4 + lg) ^ (row & 7)) * 16));
        o[nt] = __builtin_amdgcn_mfma_f32_16x16x32_bf16(vf, pf[kc], o[nt], 0, 0, 0);
      }
    __builtin_amdgcn_s_setprio(0);
  };

  stage(0, 0);
  int cur = 0;
#pragma unroll 1
  for (int kt = 0; kt <= qtB; ++kt) {
    __syncthreads();                        // buf[cur] staged; buf[cur^1] free
    if (kt < qtB) stage(kt + 1, cur ^ 1);   // loads fly under compute
    const char* Kc = (const char*)Kt[cur];
    const char* Vc = (const char*)Vt[cur];
    bf16x8 kf[2][4];
#pragma unroll
    for (int kc = 0; kc < 2; ++kc)
#pragma unroll
      for (int nt = 0; nt < 4; ++nt) {
        const int row = nt * 16 + l15;
        kf[kc][nt] = *(const bf16x8*)(Kc + row * 128 +
                                      (((kc * 4 + lg) ^ (row & 7)) * 16));
      }
    tile(qfB, kf, Vc, oB, mB, lB, kt == qtB);
    if (kt <= qtA) tile(qfA, kf, Vc, oA, mA, lA, kt == qtA);
    cur ^= 1;
  }

  // epilogue: lane holds O[q=l15][d=nt*16+lg*4+r]; ushort4 stores
  const int bq = bh / NHEAD, h = bh - bq * NHEAD;
  const float invA = 1.f / lA, invB = 1.f / lB;
#pragma unroll
  for (int nt = 0; nt < 4; ++nt) {
    ushort4 sa, sb;
    sa.x = nbf(oA[nt][0] * invA); sa.y = nbf(oA[nt][1] * invA);
    sa.z = nbf(oA[nt][2] * invA); sa.w = nbf(oA[nt][3] * invA);
    sb.x = nbf(oB[nt][0] * invB); sb.y = nbf(oB[nt][1] * invB);
    sb.z = nbf(oB[nt][2] * invB); sb.w = nbf(oB[nt][3] * invB);
    const int col = h * HSZ + nt * 16 + lg * 4;
    *(ushort4*)(AO + ((size_t)(bq * SEQ + qtA * 64 + w * 16 + l15)) * EMBED + col) = sa;
    *(ushort4*)(AO + ((size_t)(bq * SEQ + qtB * 64 + w * 16 + l15)) * EMBED + col) = sb;
  }
}

extern "C" void kernel_launch(void* const* d_in, const int* in_sizes, int n_in,
                              void* d_out, int out_size, void* d_ws, size_t ws_size,
                              hipStream_t stream) {
  const float* X  = (const float*)d_in[0];
  const float* Wq = (const float*)d_in[1];
  const float* Wk = (const float*)d_in[2];
  const float* Wv = (const float*)d_in[3];
  const float* Wo = (const float*)d_in[4];
  const float* bo = (const float*)d_in[5];
  float* out = (float*)d_out;

  const size_t NW = (size_t)EMBED * EMBED;   // 147456
  const size_t NX = (size_t)MROWS * EMBED;   // 9437184
  unsigned short* ws    = (unsigned short*)d_ws;
  unsigned short* Wqkvb = ws;                // 3*NW
  unsigned short* Wob   = Wqkvb + 3 * NW;    // NW (contiguous after Wqkvb)
  unsigned short* XbAO  = Wob + NW;          // NX: Xb (pre-attn) then AO
  unsigned short* Qb    = XbAO + NX;         // NX  [B,H,T,D]
  unsigned short* Kb    = Qb + NX;           // NX  [B,H,T,D]
  unsigned short* VTb   = Kb + NX;           // NX  [B,H,D,T] (transposed V)
  // total: 4*NW + 4*NX ushorts = 76.7 MB of d_ws

  cvtAll<<<(int)((NX + 4 * NW) / 4 / 256), 256, 0, stream>>>(
      X, Wq, Wk, Wv, Wo, Wqkvb, XbAO);

  gemm_bt<0><<<dim3(MROWS / 128, (3 * EMBED) / 128), 256, 0, stream>>>(
      XbAO, Wqkvb, Qb, Kb, VTb, nullptr, nullptr);

  attn<<<dim3(8, 144), 256, 0, stream>>>(Qb, Kb, VTb, XbAO);

  gemm_bt<1><<<dim3(MROWS / 128, EMBED / 128), 256, 0, stream>>>(
      XbAO, Wob, nullptr, nullptr, nullptr, out, bo);
}

// Round 7
// 108.762 us; speedup vs baseline: 1.2239x; 1.0011x over previous
//
#include <hip/hip_runtime.h>
#include <stdint.h>

#define EMBED 384
#define NHEAD 6
#define HSZ   64
#define BATCH 32
#define SEQ   768
#define MROWS (BATCH * SEQ)   // 24576
#define NTILE (SEQ / 64)      // 12

typedef __bf16 bf16x8 __attribute__((ext_vector_type(8)));
typedef float  f32x4  __attribute__((ext_vector_type(4)));

#define GLD16(gp, lp)                                                        \
  __builtin_amdgcn_global_load_lds(                                          \
      (const __attribute__((address_space(1))) void*)(gp),                   \
      (__attribute__((address_space(3))) void*)(lp), 16, 0, 0)

__device__ inline unsigned short nbf(float f) {   // native RNE convert
  union { __bf16 b; unsigned short s; } c; c.b = (__bf16)f; return c.s;
}
__device__ inline uint32_t pk2(float a, float b) { // -> v_cvt_pk_bf16_f32
  union { __bf16 b[2]; uint32_t u; } c;
  c.b[0] = (__bf16)a; c.b[1] = (__bf16)b; return c.u;
}

// ---------------- fused fp32 -> bf16 convert: X then Wq|Wk|Wv|Wo ------------
__global__ __launch_bounds__(256) void cvtAll(const float* __restrict__ X,
                                              const float* __restrict__ Wq,
                                              const float* __restrict__ Wk,
                                              const float* __restrict__ Wv,
                                              const float* __restrict__ Wo,
                                              unsigned short* __restrict__ dstW,
                                              unsigned short* __restrict__ dstX) {
  const int NX = MROWS * EMBED, NW = EMBED * EMBED;
  int i = (blockIdx.x * 256 + threadIdx.x) * 4;
  const float* src;
  unsigned short* dst;
  if (i < NX) {
    src = X + i; dst = dstX + i;
  } else {
    int j = i - NX;
    int wsel = j / NW, r = j - wsel * NW;
    src = ((wsel == 0) ? Wq : (wsel == 1) ? Wk : (wsel == 2) ? Wv : Wo) + r;
    dst = dstW + j;
  }
  float4 v = *reinterpret_cast<const float4*>(src);
  uint2 o;
  o.x = pk2(v.x, v.y); o.y = pk2(v.z, v.w);
  *reinterpret_cast<uint2*>(dst) = o;
}

// ---------------- GEMM: C[m,n] = sum_k A[m,k] * B[n,k]  (B stored [N][K]) ----
// 2-phase double-buffered global_load_lds staging (1 barrier per K-step).
// MODE 0: scatters Q/K bf16 (Q scaled 0.125); V written transposed VT[bh][d][t].
// MODE 1: fp32 out + bias.
template <int MODE>
__global__ __launch_bounds__(256) void gemm_bt(
    const unsigned short* __restrict__ Ab,
    const unsigned short* __restrict__ Bw,
    unsigned short* __restrict__ Qb,
    unsigned short* __restrict__ Kb,
    unsigned short* __restrict__ VT,
    float* __restrict__ Co,
    const float* __restrict__ bias) {
  __shared__ __align__(16) short SH[32768];   // 64KB: 2 bufs x (A 16KB + B 16KB)
  const int tid = threadIdx.x;
  const int lane = tid & 63;
  const int w = tid >> 6;
  const int wm = w >> 1, wn = w & 1;
  const int m0 = blockIdx.x * 128, n0 = blockIdx.y * 128;
  const int l15 = lane & 15, lg = lane >> 4;
  char* shc = (char*)SH;

  auto stage = [&](int kt, int buf) {
    short* At = SH + buf * 16384;
    short* Bt = At + 8192;
    const int k0 = kt * 64;
#pragma unroll
    for (int j = 0; j < 4; ++j) {
      const int u = j * 256 + tid;
      const int row = u >> 3, un = u & 7;
      const int sw = (un ^ (row & 7)) * 8;
      const int ub = (j * 256 + (tid & ~63)) * 8;
      GLD16(Ab + (size_t)(m0 + row) * EMBED + k0 + sw, At + ub);
      GLD16(Bw + (size_t)(n0 + row) * EMBED + k0 + sw, Bt + ub);
    }
  };

  f32x4 acc[4][4];
#pragma unroll
  for (int i = 0; i < 4; ++i)
#pragma unroll
    for (int j = 0; j < 4; ++j) acc[i][j] = f32x4{0.f, 0.f, 0.f, 0.f};

  stage(0, 0);
  int cur = 0;
#pragma unroll 1
  for (int kt = 0; kt < 6; ++kt) {
    __syncthreads();                        // drains stage(kt) [vmcnt(0) auto]
    if (kt < 5) stage(kt + 1, cur ^ 1);     // next-tile loads fly under MFMA
    const char* Ac = shc + cur * 32768;
    const char* Bc = Ac + 16384;
#pragma unroll
    for (int kc = 0; kc < 2; ++kc) {
      bf16x8 af[4], bfr[4];
#pragma unroll
      for (int mt = 0; mt < 4; ++mt) {
        const int row = wm * 64 + mt * 16 + l15;
        af[mt] = *(const bf16x8*)(Ac + row * 128 + (((kc * 4 + lg) ^ (row & 7)) * 16));
      }
#pragma unroll
      for (int nt = 0; nt < 4; ++nt) {
        const int row = wn * 64 + nt * 16 + l15;
        bfr[nt] = *(const bf16x8*)(Bc + row * 128 + (((kc * 4 + lg) ^ (row & 7)) * 16));
      }
#pragma unroll
      for (int mt = 0; mt < 4; ++mt)
#pragma unroll
        for (int nt = 0; nt < 4; ++nt)
          acc[mt][nt] = __builtin_amdgcn_mfma_f32_16x16x32_bf16(
              af[mt], bfr[nt], acc[mt][nt], 0, 0, 0);
    }
    cur ^= 1;
  }

  if (MODE == 0 && n0 >= 768) {
    // ---- V blocks: transpose via LDS (reuse buf0, 32KB), write VT coalesced --
    const int b = m0 / SEQ, t0 = m0 - b * SEQ;
    __syncthreads();
#pragma unroll
    for (int mt = 0; mt < 4; ++mt)
#pragma unroll
      for (int nt = 0; nt < 4; ++nt)
#pragma unroll
        for (int r = 0; r < 4; ++r) {
          const int tl = wm * 64 + mt * 16 + lg * 4 + r;
          const int nl = wn * 64 + nt * 16 + l15;
          *(unsigned short*)(shc + nl * 256 + (((tl >> 3) ^ (nl & 7)) * 16) +
                             (tl & 7) * 2) = nbf(acc[mt][nt][r]);
        }
    __syncthreads();
#pragma unroll
    for (int j = 0; j < 8; ++j) {
      const int u = j * 256 + tid;
      const int row = u >> 4, un = u & 15;
      int4 vv = *(const int4*)(shc + row * 256 + ((un ^ (row & 7)) * 16));
      const int cg = (n0 - 768) + row;
      const int h = cg >> 6, d = cg & 63;
      *(int4*)(VT + ((size_t)(b * NHEAD + h) * HSZ + d) * SEQ + t0 + un * 8) = vv;
    }
    return;
  }

#pragma unroll
  for (int mt = 0; mt < 4; ++mt) {
#pragma unroll
    for (int nt = 0; nt < 4; ++nt) {
#pragma unroll
      for (int r = 0; r < 4; ++r) {
        const int m = m0 + wm * 64 + mt * 16 + lg * 4 + r;
        const int n = n0 + wn * 64 + nt * 16 + l15;
        const float v = acc[mt][nt][r];
        if (MODE == 0) {
          const int which = n / EMBED;   // 0=Q, 1=K here (V handled above)
          const int c = n - which * EMBED;
          const int h = c >> 6, d = c & 63;
          const int b = m / SEQ, t = m - b * SEQ;
          const size_t off = ((size_t)((b * NHEAD + h) * SEQ + t)) * HSZ + d;
          unsigned short* dstp = (which == 0) ? Qb : Kb;
          dstp[off] = nbf(which == 0 ? v * 0.125f : v);  // fold 1/sqrt(D) into Q
        } else {
          Co[(size_t)m * EMBED + n] = v + bias[n];
        }
      }
    }
  }
}

// ---------------- flash attention, causal, paired q-tiles --------------------
// grid (8, 144): bh = (by/6)*8+bx groups same-bh blocks on one XCD.
// Joint phase (kt<=qtA): both q-tiles in one body with DUAL P buffers so the
// two softmax chains interleave; kf/vf LDS reads shared by both tiles' MFMAs.
__global__ __launch_bounds__(256, 3) void attn(const unsigned short* __restrict__ Qb,
                                               const unsigned short* __restrict__ Kb,
                                               const unsigned short* __restrict__ VT,
                                               unsigned short* __restrict__ AO) {
  __shared__ __align__(16) short Kt[2][64 * 64];   // [kv][d] swizzled, dbuf
  __shared__ __align__(16) short Vt[2][64 * 64];   // [d][kv] swizzled, dbuf
  __shared__ __align__(16) short PB[4][16 * 64];   // per-wave P (tile B)
  __shared__ __align__(16) short PA[4][16 * 64];   // per-wave P (tile A)
  const int tid = threadIdx.x, lane = tid & 63, w = tid >> 6;
  const int l15 = lane & 15, lg = lane >> 4;
  const int bh = (blockIdx.y / 6) * 8 + blockIdx.x;
  const int qtA = blockIdx.y % 6, qtB = (NTILE - 1) - qtA;
  const size_t base = (size_t)bh * SEQ * HSZ;      // Qb/Kb [bh][t][d]
  char* pwB = (char*)(&PB[w][0]);
  char* pwA = (char*)(&PA[w][0]);

  bf16x8 qfA[2], qfB[2];
#pragma unroll
  for (int kc = 0; kc < 2; ++kc) {
    qfA[kc] = *(const bf16x8*)(Qb + base + (size_t)(qtA * 64 + w * 16 + l15) * HSZ +
                               kc * 32 + lg * 8);
    qfB[kc] = *(const bf16x8*)(Qb + base + (size_t)(qtB * 64 + w * 16 + l15) * HSZ +
                               kc * 32 + lg * 8);
  }

  f32x4 oA[4], oB[4];
  float mA = -3.0e38f, lA = 0.f, mB = -3.0e38f, lB = 0.f;
#pragma unroll
  for (int nt = 0; nt < 4; ++nt) {
    oA[nt] = f32x4{0.f, 0.f, 0.f, 0.f};
    oB[nt] = f32x4{0.f, 0.f, 0.f, 0.f};
  }

  auto stage = [&](int kt, int buf) {
#pragma unroll
    for (int j = 0; j < 2; ++j) {
      const int u = j * 256 + tid;
      const int row = u >> 3, un = u & 7;
      const int sw = (un ^ (row & 7)) * 8;
      const int ub = (j * 256 + (tid & ~63)) * 8;
      GLD16(Kb + base + (size_t)(kt * 64 + row) * HSZ + sw, &Kt[buf][ub]);
      GLD16(VT + base + (size_t)row * SEQ + kt * 64 + sw, &Vt[buf][ub]);
    }
  };

  auto mask = [&](f32x4* s) {
#pragma unroll
    for (int nt = 0; nt < 4; ++nt)
#pragma unroll
      for (int r = 0; r < 4; ++r)
        if (nt * 16 + lg * 4 + r > w * 16 + l15) s[nt][r] = -3.0e38f;
  };

  // R3-verbatim softmax: update m/l/o, exp in place, pack P -> pw
  auto smax = [&](f32x4* s, f32x4* o, float& m, float& l, char* pw) {
    float mx = s[0][0];
#pragma unroll
    for (int nt = 0; nt < 4; ++nt)
#pragma unroll
      for (int r = 0; r < 4; ++r) mx = fmaxf(mx, s[nt][r]);
    mx = fmaxf(mx, __shfl_xor(mx, 16, 64));
    mx = fmaxf(mx, __shfl_xor(mx, 32, 64));
    const float mn = fmaxf(m, mx);
    const float alpha = __expf(m - mn);
    m = mn;
    float srow = 0.f;
#pragma unroll
    for (int nt = 0; nt < 4; ++nt)
#pragma unroll
      for (int r = 0; r < 4; ++r) {
        const float e = __expf(s[nt][r] - mn);
        s[nt][r] = e;
        srow += e;
      }
    srow += __shfl_xor(srow, 16, 64);
    srow += __shfl_xor(srow, 32, 64);
    l = l * alpha + srow;
#pragma unroll
    for (int nt = 0; nt < 4; ++nt) o[nt] *= alpha;
#pragma unroll
    for (int nt = 0; nt < 4; ++nt) {
      const int kv = nt * 16 + lg * 4;
      int2 pv;
      pv.x = (int)pk2(s[nt][0], s[nt][1]);
      pv.y = (int)pk2(s[nt][2], s[nt][3]);
      *(int2*)(pw + l15 * 128 + (((kv >> 3) ^ (l15 & 7)) * 16) + (kv & 7) * 2) = pv;
    }
  };

  int cur = 0;

  // joint iteration: both tiles, shared kf/vf reads, dual P buffers
  auto joint = [&](int kt, bool diagA) {
    __syncthreads();
    if (kt < qtB) stage(kt + 1, cur ^ 1);
    const char* Kc = (const char*)Kt[cur];
    const char* Vc = (const char*)Vt[cur];
    f32x4 sB[4], sA[4];
#pragma unroll
    for (int nt = 0; nt < 4; ++nt) {
      sB[nt] = f32x4{0.f, 0.f, 0.f, 0.f};
      sA[nt] = f32x4{0.f, 0.f, 0.f, 0.f};
    }
    __builtin_amdgcn_s_setprio(1);
#pragma unroll
    for (int kc = 0; kc < 2; ++kc)
#pragma unroll
      for (int nt = 0; nt < 4; ++nt) {
        const int row = nt * 16 + l15;
        bf16x8 kf = *(const bf16x8*)(Kc + row * 128 +
                                     (((kc * 4 + lg) ^ (row & 7)) * 16));
        sB[nt] = __builtin_amdgcn_mfma_f32_16x16x32_bf16(kf, qfB[kc], sB[nt], 0, 0, 0);
        sA[nt] = __builtin_amdgcn_mfma_f32_16x16x32_bf16(kf, qfA[kc], sA[nt], 0, 0, 0);
      }
    __builtin_amdgcn_s_setprio(0);
    if (diagA) mask(sA);
    smax(sB, oB, mB, lB, pwB);     // independent chains: compiler interleaves
    smax(sA, oA, mA, lA, pwA);
    asm volatile("" ::: "memory");
    bf16x8 pfB[2], pfA[2];
#pragma unroll
    for (int kc = 0; kc < 2; ++kc) {
      const int sw = ((kc * 4 + lg) ^ (l15 & 7)) * 16;
      pfB[kc] = *(const bf16x8*)(pwB + l15 * 128 + sw);
      pfA[kc] = *(const bf16x8*)(pwA + l15 * 128 + sw);
    }
    __builtin_amdgcn_s_setprio(1);
#pragma unroll
    for (int kc = 0; kc < 2; ++kc)
#pragma unroll
      for (int nt = 0; nt < 4; ++nt) {
        const int row = nt * 16 + l15;
        bf16x8 vf = *(const bf16x8*)(Vc + row * 128 +
                                     (((kc * 4 + lg) ^ (row & 7)) * 16));
        oB[nt] = __builtin_amdgcn_mfma_f32_16x16x32_bf16(vf, pfB[kc], oB[nt], 0, 0, 0);
        oA[nt] = __builtin_amdgcn_mfma_f32_16x16x32_bf16(vf, pfA[kc], oA[nt], 0, 0, 0);
      }
    __builtin_amdgcn_s_setprio(0);
    cur ^= 1;
  };

  // single iteration: tile B only (R3 tile shape, transient kf/vf)
  auto single = [&](int kt, bool diagB) {
    __syncthreads();
    if (kt < qtB) stage(kt + 1, cur ^ 1);
    const char* Kc = (const char*)Kt[cur];
    const char* Vc = (const char*)Vt[cur];
    f32x4 sB[4];
#pragma unroll
    for (int nt = 0; nt < 4; ++nt) sB[nt] = f32x4{0.f, 0.f, 0.f, 0.f};
    __builtin_amdgcn_s_setprio(1);
#pragma unroll
    for (int kc = 0; kc < 2; ++kc)
#pragma unroll
      for (int nt = 0; nt < 4; ++nt) {
        const int row = nt * 16 + l15;
        bf16x8 kf = *(const bf16x8*)(Kc + row * 128 +
                                     (((kc * 4 + lg) ^ (row & 7)) * 16));
        sB[nt] = __builtin_amdgcn_mfma_f32_16x16x32_bf16(kf, qfB[kc], sB[nt], 0, 0, 0);
      }
    __builtin_amdgcn_s_setprio(0);
    if (diagB) mask(sB);
    smax(sB, oB, mB, lB, pwB);
    asm volatile("" ::: "memory");
    bf16x8 pfB[2];
#pragma unroll
    for (int kc = 0; kc < 2; ++kc)
      pfB[kc] = *(const bf16x8*)(pwB + l15 * 128 + (((kc * 4 + lg) ^ (l15 & 7)) * 16));
    __builtin_amdgcn_s_setprio(1);
#pragma unroll
    for (int kc = 0; kc < 2; ++kc)
#pragma unroll
      for (int nt = 0; nt < 4; ++nt) {
        const int row = nt * 16 + l15;
        bf16x8 vf = *(const bf16x8*)(Vc + row * 128 +
                                     (((kc * 4 + lg) ^ (row & 7)) * 16));
        oB[nt] = __builtin_amdgcn_mfma_f32_16x16x32_bf16(vf, pfB[kc], oB[nt], 0, 0, 0);
      }
    __builtin_amdgcn_s_setprio(0);
    cur ^= 1;
  };

  stage(0, 0);
#pragma unroll 1
  for (int kt = 0; kt < qtA; ++kt) joint(kt, false);
  joint(qtA, true);
#pragma unroll 1
  for (int kt = qtA + 1; kt < qtB; ++kt) single(kt, false);
  single(qtB, true);

  // epilogue: lane holds O[q=l15][d=nt*16+lg*4+r]; ushort4 stores
  const int bq = bh / NHEAD, h = bh - bq * NHEAD;
  const float invA = 1.f / lA, invB = 1.f / lB;
#pragma unroll
  for (int nt = 0; nt < 4; ++nt) {
    ushort4 sa, sb;
    sa.x = nbf(oA[nt][0] * invA); sa.y = nbf(oA[nt][1] * invA);
    sa.z = nbf(oA[nt][2] * invA); sa.w = nbf(oA[nt][3] * invA);
    sb.x = nbf(oB[nt][0] * invB); sb.y = nbf(oB[nt][1] * invB);
    sb.z = nbf(oB[nt][2] * invB); sb.w = nbf(oB[nt][3] * invB);
    const int col = h * HSZ + nt * 16 + lg * 4;
    *(ushort4*)(AO + ((size_t)(bq * SEQ + qtA * 64 + w * 16 + l15)) * EMBED + col) = sa;
    *(ushort4*)(AO + ((size_t)(bq * SEQ + qtB * 64 + w * 16 + l15)) * EMBED + col) = sb;
  }
}

extern "C" void kernel_launch(void* const* d_in, const int* in_sizes, int n_in,
                              void* d_out, int out_size, void* d_ws, size_t ws_size,
                              hipStream_t stream) {
  const float* X  = (const float*)d_in[0];
  const float* Wq = (const float*)d_in[1];
  const float* Wk = (const float*)d_in[2];
  const float* Wv = (const float*)d_in[3];
  const float* Wo = (const float*)d_in[4];
  const float* bo = (const float*)d_in[5];
  float* out = (float*)d_out;

  const size_t NW = (size_t)EMBED * EMBED;   // 147456
  const size_t NX = (size_t)MROWS * EMBED;   // 9437184
  unsigned short* ws    = (unsigned short*)d_ws;
  unsigned short* Wqkvb = ws;                // 3*NW
  unsigned short* Wob   = Wqkvb + 3 * NW;    // NW (contiguous after Wqkvb)
  unsigned short* XbAO  = Wob + NW;          // NX: Xb (pre-attn) then AO
  unsigned short* Qb    = XbAO + NX;         // NX  [B,H,T,D]
  unsigned short* Kb    = Qb + NX;           // NX  [B,H,T,D]
  unsigned short* VTb   = Kb + NX;           // NX  [B,H,D,T] (transposed V)
  // total: 4*NW + 4*NX ushorts = 76.7 MB of d_ws

  cvtAll<<<(int)((NX + 4 * NW) / 4 / 256), 256, 0, stream>>>(
      X, Wq, Wk, Wv, Wo, Wqkvb, XbAO);

  gemm_bt<0><<<dim3(MROWS / 128, (3 * EMBED) / 128), 256, 0, stream>>>(
      XbAO, Wqkvb, Qb, Kb, VTb, nullptr, nullptr);

  attn<<<dim3(8, 144), 256, 0, stream>>>(Qb, Kb, VTb, XbAO);

  gemm_bt<1><<<dim3(MROWS / 128, EMBED / 128), 256, 0, stream>>>(
      XbAO, Wob, nullptr, nullptr, nullptr, out, bo);
}